// Round 1
// baseline (283.509 us; speedup 1.0000x reference)
//
#include <hip/hip_runtime.h>

// ---------------------------------------------------------------------------
// CostVolume (PointPWC-style) fused kernel for MI355X (gfx950).
// Design:
//  - pack_weights: one-shot kernel packs all MLP weights into d_ws as
//    bf16 MFMA B-fragments + f32 "combo" matrices for the linear-factored
//    first layers (d = xq - xp is linear => only euc term is truly per-pair).
//  - cvkernel: one workgroup per 32-point tile. Per-pair GEMMs (K=64/128)
//    via v_mfma_f32_16x16x32_bf16, activations staged in XOR-swizzled bf16
//    LDS buffers, f32 logits + softmax + weighted aggregation.
// ---------------------------------------------------------------------------

typedef __attribute__((ext_vector_type(8))) short   short8;
typedef __attribute__((ext_vector_type(8))) __bf16  bf16x8;
typedef __attribute__((ext_vector_type(4))) float   f32x4;
typedef __attribute__((ext_vector_type(4))) float   float4v;
typedef __attribute__((ext_vector_type(2))) unsigned int uint2v;
typedef __attribute__((ext_vector_type(4))) unsigned int uint4v;

#define S_LEN 8192
#define TPB   256

// ---- workspace byte offsets (written by pack_weights) ----
// bf16 B-fragment packs, contiguous from 0:
//   L11 [0,8192) L20 [8192,24576) L21 [24576,32768) L30A [32768,40960)
//   L31 [40960,49152) WF1 [49152,57344) WF2 [57344,65536)
//   W30B [65536,73728) W30C [73728,81920)
#define WS_WF1    49152
#define WS_WF2    57344
#define WS_W30B   65536
#define WS_W30C   73728
#define WS_F32    81920   // 1344 f32: A1x A2x C1x C2x D1x D2x (6*192), we1 ee ge (3*64)

// ---- LDS byte offsets ----
#define OFF_L11   0
#define OFF_L20   8192
#define OFF_L21   24576
#define OFF_L30A  32768
#define OFF_L31   40960
#define OFF_F1B   49152   // [32][64] bf16 swizzled
#define OFF_F2B   53248
#define OFF_AGGB  57344   // [32][64] bf16 swizzled
#define OFF_ABUF  61440   // [64][64] bf16 swizzled
#define OFF_BBUF  69632
#define OFF_CBUF  77824
#define OFF_SBUF  86016   // [64][66] f32 logits
#define SB_STRIDE 66
#define OFF_A1F   102912  // [32][64] f32 (stage2: v1)
#define OFF_A2F   111104  // [32][64] f32 (stage2: v2)
#define OFF_C1F   119296  // [32][64] f32 (stage2: d1)
#define OFF_C2F   127488  // [32][64] f32 (stage2: d2)
#define OFF_AGGF  135680  // [32][64] f32
#define OFF_X1    143872  // [32][4] f32
#define OFF_X2    144384
#define OFF_EUC   144896  // [64] f32
#define OFF_BIAS  145152  // 8*64 f32: b10 bx1 b11 b20 b21 bx2 b30 b31
#define OFF_COMB  147200  // 1344 f32
#define LDS_TOTAL 152576

__device__ __forceinline__ unsigned short f2bf(float f){
  unsigned int u = __float_as_uint(f);
  u += 0x7fffu + ((u >> 16) & 1u);
  return (unsigned short)(u >> 16);
}
__device__ __forceinline__ float bf2f(unsigned short h){
  return __uint_as_float(((unsigned int)h) << 16);
}

// swizzled bf16 [rows][64] helpers: byte = (r*64+c)*2 ^ ((r&7)<<4)
__device__ __forceinline__ bf16x8 ldsA(const char* base, int r, int k){
  short8 a = *(const short8*)(base + ((((r << 6) + k) << 1) ^ ((r & 7) << 4)));
  return __builtin_bit_cast(bf16x8, a);
}
__device__ __forceinline__ void stBF(char* base, int r, int c, float v){
  *(unsigned short*)(base + ((((r << 6) + c) << 1) ^ ((r & 7) << 4))) = f2bf(v);
}
__device__ __forceinline__ float ldBF(const char* base, int r, int c){
  return bf2f(*(const unsigned short*)(base + ((((r << 6) + c) << 1) ^ ((r & 7) << 4))));
}
__device__ __forceinline__ void stBF4(char* base, int r, int c4, float4v v){
  uint2v u;
  u.x = (unsigned)f2bf(v.x) | ((unsigned)f2bf(v.y) << 16);
  u.y = (unsigned)f2bf(v.z) | ((unsigned)f2bf(v.w) << 16);
  *(uint2v*)(base + ((((r << 6) + c4) << 1) ^ ((r & 7) << 4))) = u;
}

// K=64 GEMM: acc[cb] += A(16x64 from rbase) * Bpack ; out cols = cb*16+(lane&15)
__device__ __forceinline__ void gemm_k64(f32x4 acc[4], const char* Asrc,
                                         const char* Bp, int rbase, int lane){
  const int r  = rbase + (lane & 15);
  const int kg = (lane >> 4) << 3;
#pragma unroll
  for (int kb = 0; kb < 2; ++kb){
    bf16x8 a = ldsA(Asrc, r, kb * 32 + kg);
#pragma unroll
    for (int cb = 0; cb < 4; ++cb){
      short8 braw = *(const short8*)(Bp + (((kb << 2) + cb) * 64 + lane) * 16);
      acc[cb] = __builtin_amdgcn_mfma_f32_16x16x32_bf16(
          a, __builtin_bit_cast(bf16x8, braw), acc[cb], 0, 0, 0);
    }
  }
}

__global__ void pack_weights(const float* __restrict__ w10, const float* __restrict__ w11,
                             const float* __restrict__ wx1, const float* __restrict__ wx2,
                             const float* __restrict__ w20, const float* __restrict__ w21,
                             const float* __restrict__ w30, const float* __restrict__ w31,
                             unsigned char* __restrict__ ws)
{
  for (int i = blockIdx.x * blockDim.x + threadIdx.x; i < 42304;
       i += gridDim.x * blockDim.x){
    if (i < 40960){
      const float* src; int stride, coff, e;
      if      (i <  4096){ src = w11; stride =  64; coff =   0; e = i;         }
      else if (i < 12288){ src = w20; stride = 128; coff =   0; e = i -  4096; }
      else if (i < 16384){ src = w21; stride =  64; coff =   0; e = i - 12288; }
      else if (i < 20480){ src = w30; stride = 192; coff =   0; e = i - 16384; }
      else if (i < 24576){ src = w31; stride =  64; coff =   0; e = i - 20480; }
      else if (i < 28672){ src = w10; stride = 138; coff =  10; e = i - 24576; }
      else if (i < 32768){ src = w10; stride = 138; coff =  74; e = i - 28672; }
      else if (i < 36864){ src = w30; stride = 192; coff =  64; e = i - 32768; }
      else               { src = w30; stride = 192; coff = 128; e = i - 36864; }
      int j = e & 7, lane = (e >> 3) & 63, cb = (e >> 9) & 3, kb = e >> 11;
      int k = kb * 32 + ((lane >> 4) << 3) + j;
      int o = cb * 16 + (lane & 15);
      ((unsigned short*)ws)[i] = f2bf(src[o * stride + coff + k]);
    } else {
      int f = i - 40960; float v;
      if (f < 1152){
        int grp = f / 192, rem = f % 192, d = rem >> 6, o = rem & 63;
        if      (grp == 0) v = w10[o*138 + d]     - w10[o*138 + 6 + d];
        else if (grp == 1) v = w10[o*138 + 3 + d] + w10[o*138 + 6 + d];
        else if (grp == 2) v = wx1[o*10 + d]      - wx1[o*10 + 6 + d];
        else if (grp == 3) v = wx1[o*10 + 3 + d]  + wx1[o*10 + 6 + d];
        else if (grp == 4) v = wx2[o*10 + d]      - wx2[o*10 + 6 + d];
        else               v = wx2[o*10 + 3 + d]  + wx2[o*10 + 6 + d];
      }
      else if (f < 1216) v = w10[(f - 1152)*138 + 9];
      else if (f < 1280) v = wx1[(f - 1216)*10  + 9];
      else               v = wx2[(f - 1280)*10  + 9];
      ((float*)(ws + WS_F32))[f] = v;
    }
  }
}

__global__ __launch_bounds__(TPB) void cvkernel(
    const float* __restrict__ xyz1, const float* __restrict__ feat1,
    const float* __restrict__ xyz2, const float* __restrict__ feat2,
    const float* __restrict__ b10v, const float* __restrict__ bx1v,
    const float* __restrict__ b11v, const float* __restrict__ b20v,
    const float* __restrict__ b21v, const float* __restrict__ bx2v,
    const float* __restrict__ b30v, const float* __restrict__ b31v,
    const char*  __restrict__ ws,   float* __restrict__ out)
{
  extern __shared__ __align__(16) char smem[];
  const int tid  = threadIdx.x;
  const int lane = tid & 63;
  const int wave = tid >> 6;
  const int tile = blockIdx.x;
  const int b    = tile >> 8;          // 256 tiles per batch
  const int s0   = (tile & 255) << 5;

  float* x1    = (float*)(smem + OFF_X1);
  float* x2    = (float*)(smem + OFF_X2);
  float* a1f   = (float*)(smem + OFF_A1F);
  float* a2f   = (float*)(smem + OFF_A2F);
  float* c1f   = (float*)(smem + OFF_C1F);
  float* c2f   = (float*)(smem + OFF_C2F);
  float* aggf  = (float*)(smem + OFF_AGGF);
  float* Sb    = (float*)(smem + OFF_SBUF);
  float* biasL = (float*)(smem + OFF_BIAS);
  float* comb  = (float*)(smem + OFF_COMB);
  float* eucb  = (float*)(smem + OFF_EUC);

  // ---- stage constants into LDS ----
  { // Bpack (L11..L31): 49152 B
    const uint4v* src = (const uint4v*)ws;
    uint4v*       dst = (uint4v*)smem;
    for (int i = tid; i < 3072; i += TPB) dst[i] = src[i];
  }
  if (tid < 64){
    biasL[0*64+tid] = b10v[tid]; biasL[1*64+tid] = bx1v[tid];
    biasL[2*64+tid] = b11v[tid]; biasL[3*64+tid] = b20v[tid];
    biasL[4*64+tid] = b21v[tid]; biasL[5*64+tid] = bx2v[tid];
    biasL[6*64+tid] = b30v[tid]; biasL[7*64+tid] = b31v[tid];
  }
  { const float* src = (const float*)(ws + WS_F32);
    for (int i = tid; i < 1344; i += TPB) comb[i] = src[i]; }
  if (tid < 32){
#pragma unroll
    for (int d = 0; d < 3; ++d) x1[tid*4+d] = xyz1[(b*3+d)*S_LEN + s0 + tid];
    x1[tid*4+3] = 0.f;
  } else if (tid < 64){
    int p = tid - 32;
#pragma unroll
    for (int d = 0; d < 3; ++d) x2[p*4+d] = xyz2[(b*3+d)*S_LEN + s0 + p];
    x2[p*4+3] = 0.f;
  }
  for (int i = tid; i < 2048; i += TPB){
    int ch = i >> 5, p = i & 31;
    stBF(smem + OFF_F1B, p, ch, feat1[(b*64+ch)*S_LEN + s0 + p]);
    stBF(smem + OFF_F2B, p, ch, feat2[(b*64+ch)*S_LEN + s0 + p]);
  }
  __syncthreads();

  // ---- per-point precompute: a1 = Wf1*f1, a2 = Wf2*f2 (MFMA, M=32) ----
  {
    const char* Ab  = (wave < 2) ? (smem + OFF_F1B) : (smem + OFF_F2B);
    const char* Bg  = ws + ((wave < 2) ? WS_WF1 : WS_WF2);
    float* dstf     = (wave < 2) ? a1f : a2f;
    const int rt    = wave & 1;
    f32x4 acc[4];
#pragma unroll
    for (int cb = 0; cb < 4; ++cb) acc[cb] = (f32x4){0.f,0.f,0.f,0.f};
    gemm_k64(acc, Ab, Bg, rt * 16, lane);
#pragma unroll
    for (int cb = 0; cb < 4; ++cb)
#pragma unroll
      for (int v = 0; v < 4; ++v){
        int row = rt*16 + ((lane >> 4) << 2) + v;
        int col = (cb << 4) + (lane & 15);
        dstf[row*64 + col] = acc[cb][v];
      }
  }
  __syncthreads();
  // x-parts (K=3) + xyz-encoder per-point terms
  for (int i = tid; i < 2048; i += TPB){
    int o = i & 63, p = i >> 6;
    float xa = x1[p*4], xb = x1[p*4+1], xc = x1[p*4+2];
    float ya = x2[p*4], yb = x2[p*4+1], yc = x2[p*4+2];
    a1f[p*64+o] += comb[      o]*xa + comb[ 64+o]*xb + comb[128+o]*xc;
    a2f[p*64+o] += comb[192+  o]*ya + comb[256+o]*yb + comb[320+o]*yc;
    c1f[p*64+o]  = comb[384+  o]*xa + comb[448+o]*xb + comb[512+o]*xc;
    c2f[p*64+o]  = comb[576+  o]*ya + comb[640+o]*yb + comb[704+o]*yc;
  }
  __syncthreads();

  const float* we1 = comb + 1152;
  const float* eev = comb + 1216;
  const float* gev = comb + 1280;
  const int myc4 = (tid & 15) << 2;
  const float4v we4 = *(const float4v*)(we1 + myc4);
  const float4v ee4 = *(const float4v*)(eev + myc4);
  const float4v ge4 = *(const float4v*)(gev + myc4);
  const float4v b04 = *(const float4v*)(biasL + 0*64 + myc4);
  const float4v b14 = *(const float4v*)(biasL + 1*64 + myc4);
  const float4v b54 = *(const float4v*)(biasL + 5*64 + myc4);

  // ================= stage 1: 16 chunks of 64 pair-rows =================
  for (int cc = 0; cc < 16; ++cc){
    const int p2 = cc << 1;
    if (tid < 64){
      int q = tid & 31, p = p2 + (tid >> 5);
      float dx = x2[q*4]-x1[p*4], dy = x2[q*4+1]-x1[p*4+1], dz = x2[q*4+2]-x1[p*4+2];
      eucb[tid] = sqrtf(dx*dx + dy*dy + dz*dz + 1e-20f);
    }
    __syncthreads();
    // h1 -> ABUF, e -> BBUF
    for (int i = tid; i < 1024; i += TPB){
      int rr = i >> 4, c4 = (i & 15) << 2;
      int q = rr & 31, p = p2 + (rr >> 5);
      float eu = eucb[rr];
      float4v A1 = *(const float4v*)(a1f + p*64 + c4);
      float4v A2 = *(const float4v*)(a2f + q*64 + c4);
      float4v C1 = *(const float4v*)(c1f + p*64 + c4);
      float4v C2 = *(const float4v*)(c2f + q*64 + c4);
      float4v hv = A1 + A2 + we4*eu + b04;
      float4v ev = C1 + C2 + ee4*eu + b14;
      hv.x = fmaxf(hv.x,0.f); hv.y = fmaxf(hv.y,0.f); hv.z = fmaxf(hv.z,0.f); hv.w = fmaxf(hv.w,0.f);
      ev.x = fmaxf(ev.x,0.f); ev.y = fmaxf(ev.y,0.f); ev.z = fmaxf(ev.z,0.f); ev.w = fmaxf(ev.w,0.f);
      stBF4(smem + OFF_ABUF, rr, c4, hv);
      stBF4(smem + OFF_BBUF, rr, c4, ev);
    }
    __syncthreads();
    { // mlp1_1: h2 = relu(W11*h1 + b11) -> CBUF
      f32x4 acc[4];
#pragma unroll
      for (int cb = 0; cb < 4; ++cb) acc[cb] = (f32x4){0.f,0.f,0.f,0.f};
      gemm_k64(acc, smem + OFF_ABUF, smem + OFF_L11, wave*16, lane);
#pragma unroll
      for (int cb = 0; cb < 4; ++cb)
#pragma unroll
        for (int v = 0; v < 4; ++v){
          int row = wave*16 + ((lane >> 4) << 2) + v;
          int col = (cb << 4) + (lane & 15);
          stBF(smem + OFF_CBUF, row, col, fmaxf(acc[cb][v] + biasL[2*64+col], 0.f));
        }
    }
    __syncthreads();
    { // mlp2_0: c1out = relu(W20*[e;h2] + b20) -> ABUF
      f32x4 acc[4];
#pragma unroll
      for (int cb = 0; cb < 4; ++cb) acc[cb] = (f32x4){0.f,0.f,0.f,0.f};
      const int r  = wave*16 + (lane & 15);
      const int kg = (lane >> 4) << 3;
#pragma unroll
      for (int kb = 0; kb < 4; ++kb){
        const char* Asrc = (kb < 2) ? (smem + OFF_BBUF) : (smem + OFF_CBUF);
        bf16x8 a = ldsA(Asrc, r, (kb & 1)*32 + kg);
#pragma unroll
        for (int cb = 0; cb < 4; ++cb){
          short8 braw = *(const short8*)(smem + OFF_L20 + (((kb << 2) + cb)*64 + lane)*16);
          acc[cb] = __builtin_amdgcn_mfma_f32_16x16x32_bf16(
              a, __builtin_bit_cast(bf16x8, braw), acc[cb], 0, 0, 0);
        }
      }
#pragma unroll
      for (int cb = 0; cb < 4; ++cb)
#pragma unroll
        for (int v = 0; v < 4; ++v){
          int row = wave*16 + ((lane >> 4) << 2) + v;
          int col = (cb << 4) + (lane & 15);
          stBF(smem + OFF_ABUF, row, col, fmaxf(acc[cb][v] + biasL[3*64+col], 0.f));
        }
    }
    __syncthreads();
    { // mlp2_1: logits -> Sb (f32)
      f32x4 acc[4];
#pragma unroll
      for (int cb = 0; cb < 4; ++cb) acc[cb] = (f32x4){0.f,0.f,0.f,0.f};
      gemm_k64(acc, smem + OFF_ABUF, smem + OFF_L21, wave*16, lane);
#pragma unroll
      for (int cb = 0; cb < 4; ++cb)
#pragma unroll
        for (int v = 0; v < 4; ++v){
          int row = wave*16 + ((lane >> 4) << 2) + v;
          int col = (cb << 4) + (lane & 15);
          Sb[row*SB_STRIDE + col] = fmaxf(acc[cb][v] + biasL[4*64+col], 0.f);
        }
    }
    __syncthreads();
    // softmax over q + aggregation
    if (tid < 128){
      int pp = tid >> 6, ch = tid & 63, p = p2 + pp;
      float m = -1e30f;
      for (int q = 0; q < 32; ++q) m = fmaxf(m, Sb[(pp*32+q)*SB_STRIDE + ch]);
      float den = 0.f, num = 0.f;
      for (int q = 0; q < 32; ++q){
        int rr = pp*32 + q;
        float e = __expf(Sb[rr*SB_STRIDE + ch] - m);
        den += e;
        num += e * ldBF(smem + OFF_CBUF, rr, ch);
      }
      float ag = num / den;
      aggf[p*64 + ch] = ag;
      stBF(smem + OFF_AGGB, p, ch, ag);
    }
    __syncthreads();
  }

  // ---- stage-2 per-point precompute: d1/d2 (K=3), v1/v2 (MFMA) ----
  for (int i = tid; i < 2048; i += TPB){
    int o = i & 63, p = i >> 6;
    float xa = x1[p*4], xb = x1[p*4+1], xc = x1[p*4+2];
    c1f[p*64+o] = comb[768+o]*xa + comb[832+o]*xb + comb[896+o]*xc;
    c2f[p*64+o] = comb[960+o]*xa + comb[1024+o]*xb + comb[1088+o]*xc;
  }
  {
    const char* Ab = (wave < 2) ? (smem + OFF_F1B) : (smem + OFF_AGGB);
    const char* Bg = ws + ((wave < 2) ? WS_W30B : WS_W30C);
    float* dstf    = (wave < 2) ? a1f : a2f;   // v1 / v2
    const int rt   = wave & 1;
    f32x4 acc[4];
#pragma unroll
    for (int cb = 0; cb < 4; ++cb) acc[cb] = (f32x4){0.f,0.f,0.f,0.f};
    gemm_k64(acc, Ab, Bg, rt*16, lane);
#pragma unroll
    for (int cb = 0; cb < 4; ++cb)
#pragma unroll
      for (int v = 0; v < 4; ++v){
        int row = rt*16 + ((lane >> 4) << 2) + v;
        int col = (cb << 4) + (lane & 15);
        dstf[row*64 + col] = acc[cb][v];
      }
  }
  __syncthreads();

  // ================= stage 2: 16 chunks of 64 pair-rows =================
  for (int cc = 0; cc < 16; ++cc){
    const int p2 = cc << 1;
    if (tid < 64){
      int q = tid & 31, p = p2 + (tid >> 5);
      float dx = x1[q*4]-x1[p*4], dy = x1[q*4+1]-x1[p*4+1], dz = x1[q*4+2]-x1[p*4+2];
      eucb[tid] = sqrtf(dx*dx + dy*dy + dz*dz + 1e-20f);
    }
    __syncthreads();
    // e2 -> ABUF
    for (int i = tid; i < 1024; i += TPB){
      int rr = i >> 4, c4 = (i & 15) << 2;
      int q = rr & 31, p = p2 + (rr >> 5);
      float eu = eucb[rr];
      float4v C1 = *(const float4v*)(c1f + p*64 + c4);
      float4v C2 = *(const float4v*)(c2f + q*64 + c4);
      float4v ev = C1 + C2 + ge4*eu + b54;
      ev.x = fmaxf(ev.x,0.f); ev.y = fmaxf(ev.y,0.f); ev.z = fmaxf(ev.z,0.f); ev.w = fmaxf(ev.w,0.f);
      stBF4(smem + OFF_ABUF, rr, c4, ev);
    }
    __syncthreads();
    { // mlp3_0: c3 = relu(W30a*e2 + v1[p] + v2[r] + b30) -> BBUF
      f32x4 acc[4];
#pragma unroll
      for (int cb = 0; cb < 4; ++cb) acc[cb] = (f32x4){0.f,0.f,0.f,0.f};
      gemm_k64(acc, smem + OFF_ABUF, smem + OFF_L30A, wave*16, lane);
#pragma unroll
      for (int cb = 0; cb < 4; ++cb)
#pragma unroll
        for (int v = 0; v < 4; ++v){
          int row = wave*16 + ((lane >> 4) << 2) + v;
          int col = (cb << 4) + (lane & 15);
          int p = p2 + (row >> 5), q = row & 31;
          float c3 = acc[cb][v] + a1f[p*64+col] + a2f[q*64+col] + biasL[6*64+col];
          stBF(smem + OFF_BBUF, row, col, fmaxf(c3, 0.f));
        }
    }
    __syncthreads();
    { // mlp3_1: logits -> Sb
      f32x4 acc[4];
#pragma unroll
      for (int cb = 0; cb < 4; ++cb) acc[cb] = (f32x4){0.f,0.f,0.f,0.f};
      gemm_k64(acc, smem + OFF_BBUF, smem + OFF_L31, wave*16, lane);
#pragma unroll
      for (int cb = 0; cb < 4; ++cb)
#pragma unroll
        for (int v = 0; v < 4; ++v){
          int row = wave*16 + ((lane >> 4) << 2) + v;
          int col = (cb << 4) + (lane & 15);
          Sb[row*SB_STRIDE + col] = fmaxf(acc[cb][v] + biasL[7*64+col], 0.f);
        }
    }
    __syncthreads();
    // masked softmax over r != p + output
    if (tid < 128){
      int pp = tid >> 6, ch = tid & 63, p = p2 + pp;
      float m = -1e30f;
      for (int q = 0; q < 32; ++q)
        if (q != p) m = fmaxf(m, Sb[(pp*32+q)*SB_STRIDE + ch]);
      float den = 0.f, num = 0.f;
      for (int q = 0; q < 32; ++q)
        if (q != p){
          float e = __expf(Sb[(pp*32+q)*SB_STRIDE + ch] - m);
          den += e;
          num += e * aggf[q*64 + ch];
        }
      out[(b*64 + ch)*S_LEN + s0 + p] = num / den;
    }
    __syncthreads();
  }
}

extern "C" void kernel_launch(void* const* d_in, const int* in_sizes, int n_in,
                              void* d_out, int out_size, void* d_ws, size_t ws_size,
                              hipStream_t stream)
{
  const float* xyz1 = (const float*)d_in[0];
  const float* feat1= (const float*)d_in[1];
  const float* xyz2 = (const float*)d_in[2];
  const float* feat2= (const float*)d_in[3];
  const float* w10  = (const float*)d_in[4];
  const float* b10  = (const float*)d_in[5];
  const float* w11  = (const float*)d_in[6];
  const float* b11  = (const float*)d_in[7];
  const float* wx1  = (const float*)d_in[8];
  const float* bx1  = (const float*)d_in[9];
  const float* wx2  = (const float*)d_in[10];
  const float* bx2  = (const float*)d_in[11];
  const float* w20  = (const float*)d_in[12];
  const float* b20  = (const float*)d_in[13];
  const float* w21  = (const float*)d_in[14];
  const float* b21  = (const float*)d_in[15];
  const float* w30  = (const float*)d_in[16];
  const float* b30  = (const float*)d_in[17];
  const float* w31  = (const float*)d_in[18];
  const float* b31  = (const float*)d_in[19];

  (void)hipFuncSetAttribute(reinterpret_cast<const void*>(cvkernel),
                            hipFuncAttributeMaxDynamicSharedMemorySize, LDS_TOTAL);

  hipLaunchKernelGGL(pack_weights, dim3(64), dim3(256), 0, stream,
                     w10, w11, wx1, wx2, w20, w21, w30, w31, (unsigned char*)d_ws);
  hipLaunchKernelGGL(cvkernel, dim3(512), dim3(TPB), LDS_TOTAL, stream,
                     xyz1, feat1, xyz2, feat2,
                     b10, bx1, b11, b20, b21, bx2, b30, b31,
                     (const char*)d_ws, (float*)d_out);
}

// Round 2
// 171.938 us; speedup vs baseline: 1.6489x; 1.6489x over previous
//
#include <hip/hip_runtime.h>

// ---------------------------------------------------------------------------
// CostVolume fused kernel, R2: wave-independent pipeline.
// Each wave owns one center point p per chunk and runs the full MLP pipeline
// on its private 32x64 LDS buffers -> no __syncthreads inside the chunk loops.
// Softmax + aggregation fully in registers (butterfly shfl over lane>>4).
// ---------------------------------------------------------------------------

typedef __attribute__((ext_vector_type(8))) short   short8;
typedef __attribute__((ext_vector_type(8))) __bf16  bf16x8;
typedef __attribute__((ext_vector_type(4))) float   f32x4;
typedef __attribute__((ext_vector_type(4))) float   float4v;
typedef __attribute__((ext_vector_type(2))) unsigned int uint2v;
typedef __attribute__((ext_vector_type(4))) unsigned int uint4v;

#define S_LEN 8192
#define TPB   256

// ---- workspace byte offsets (written by pack_weights) ----
#define WS_WF1    49152
#define WS_WF2    57344
#define WS_W30B   65536
#define WS_W30C   73728
#define WS_F32    81920   // 1344 f32

// ---- LDS byte offsets ----
#define OFF_L11   0
#define OFF_L20   8192
#define OFF_L21   24576
#define OFF_L30A  32768
#define OFF_L31   40960
#define OFF_ACT   49152   // 4 waves x 12288 (A:4K, B:4K, C:4K) bf16 swizzled [32][64]
#define OFF_F1B   98304   // [32][64] bf16 swizzled
#define OFF_F2B   102400
#define OFF_AGGB  106496  // [32][64] bf16 swizzled
#define OFF_A1F   110592  // [32][64] f32
#define OFF_A2F   118784
#define OFF_C1F   126976
#define OFF_C2F   135168
#define OFF_OUTB  143360  // [32][66] f32
#define OFF_X1    151808  // [32][4] f32
#define OFF_X2    152320
#define OFF_BIAS  152832  // 8*64 f32
#define OFF_COMB  154880  // 1344 f32
#define LDS_TOTAL 160256

__device__ __forceinline__ unsigned short f2bf(float f){
  unsigned int u = __float_as_uint(f);
  u += 0x7fffu + ((u >> 16) & 1u);
  return (unsigned short)(u >> 16);
}
__device__ __forceinline__ float bf2f(unsigned short h){
  return __uint_as_float(((unsigned int)h) << 16);
}

// swizzled bf16 [rows][64] helpers: byte = (r*64+c)*2 ^ ((r&7)<<4)
__device__ __forceinline__ bf16x8 ldsA(const char* base, int r, int k){
  short8 a = *(const short8*)(base + ((((r << 6) + k) << 1) ^ ((r & 7) << 4)));
  return __builtin_bit_cast(bf16x8, a);
}
__device__ __forceinline__ void stBF(char* base, int r, int c, float v){
  *(unsigned short*)(base + ((((r << 6) + c) << 1) ^ ((r & 7) << 4))) = f2bf(v);
}
__device__ __forceinline__ float ldBF(const char* base, int r, int c){
  return bf2f(*(const unsigned short*)(base + ((((r << 6) + c) << 1) ^ ((r & 7) << 4))));
}
__device__ __forceinline__ void stBF4(char* base, int r, int c4, float4v v){
  uint2v u;
  u.x = (unsigned)f2bf(v.x) | ((unsigned)f2bf(v.y) << 16);
  u.y = (unsigned)f2bf(v.z) | ((unsigned)f2bf(v.w) << 16);
  *(uint2v*)(base + ((((r << 6) + c4) << 1) ^ ((r & 7) << 4))) = u;
}

// old-style K=64 GEMM over 16 rows (precompute phases), B read per row-tile
__device__ __forceinline__ void gemm_k64(f32x4 acc[4], const char* Asrc,
                                         const char* Bp, int rbase, int lane){
  const int r  = rbase + (lane & 15);
  const int kg = (lane >> 4) << 3;
#pragma unroll
  for (int kb = 0; kb < 2; ++kb){
    bf16x8 a = ldsA(Asrc, r, kb * 32 + kg);
#pragma unroll
    for (int cb = 0; cb < 4; ++cb){
      short8 braw = *(const short8*)(Bp + (((kb << 2) + cb) * 64 + lane) * 16);
      acc[cb] = __builtin_amdgcn_mfma_f32_16x16x32_bf16(
          a, __builtin_bit_cast(bf16x8, braw), acc[cb], 0, 0, 0);
    }
  }
}

// load one K=64 B-pack (8 fragments) into registers
__device__ __forceinline__ void load_B8(bf16x8 Breg[8], const char* Bp, int lane){
#pragma unroll
  for (int u = 0; u < 8; ++u)
    Breg[u] = __builtin_bit_cast(bf16x8,
        *(const short8*)(Bp + (u * 64 + lane) * 16));
}

// wave-local K=64 GEMM over the wave's 32 rows, B in registers
__device__ __forceinline__ void gemm32_k64(f32x4 acc[2][4], const char* Asrc,
                                           const bf16x8 Breg[8], int lane){
  const int kg = (lane >> 4) << 3;
#pragma unroll
  for (int t = 0; t < 2; ++t){
    const int r = t * 16 + (lane & 15);
#pragma unroll
    for (int kb = 0; kb < 2; ++kb){
      bf16x8 a = ldsA(Asrc, r, kb * 32 + kg);
#pragma unroll
      for (int cb = 0; cb < 4; ++cb)
        acc[t][cb] = __builtin_amdgcn_mfma_f32_16x16x32_bf16(
            a, Breg[kb * 4 + cb], acc[t][cb], 0, 0, 0);
    }
  }
}

__device__ __forceinline__ float red_max(float x){
  x = fmaxf(x, __shfl_xor(x, 16, 64));
  x = fmaxf(x, __shfl_xor(x, 32, 64));
  return x;
}
__device__ __forceinline__ float red_sum(float x){
  x += __shfl_xor(x, 16, 64);
  x += __shfl_xor(x, 32, 64);
  return x;
}

__global__ void pack_weights(const float* __restrict__ w10, const float* __restrict__ w11,
                             const float* __restrict__ wx1, const float* __restrict__ wx2,
                             const float* __restrict__ w20, const float* __restrict__ w21,
                             const float* __restrict__ w30, const float* __restrict__ w31,
                             unsigned char* __restrict__ ws)
{
  for (int i = blockIdx.x * blockDim.x + threadIdx.x; i < 42304;
       i += gridDim.x * blockDim.x){
    if (i < 40960){
      const float* src; int stride, coff, e;
      if      (i <  4096){ src = w11; stride =  64; coff =   0; e = i;         }
      else if (i < 12288){ src = w20; stride = 128; coff =   0; e = i -  4096; }
      else if (i < 16384){ src = w21; stride =  64; coff =   0; e = i - 12288; }
      else if (i < 20480){ src = w30; stride = 192; coff =   0; e = i - 16384; }
      else if (i < 24576){ src = w31; stride =  64; coff =   0; e = i - 20480; }
      else if (i < 28672){ src = w10; stride = 138; coff =  10; e = i - 24576; }
      else if (i < 32768){ src = w10; stride = 138; coff =  74; e = i - 28672; }
      else if (i < 36864){ src = w30; stride = 192; coff =  64; e = i - 32768; }
      else               { src = w30; stride = 192; coff = 128; e = i - 36864; }
      int j = e & 7, lane = (e >> 3) & 63, cb = (e >> 9) & 3, kb = e >> 11;
      int k = kb * 32 + ((lane >> 4) << 3) + j;
      int o = cb * 16 + (lane & 15);
      ((unsigned short*)ws)[i] = f2bf(src[o * stride + coff + k]);
    } else {
      int f = i - 40960; float v;
      if (f < 1152){
        int grp = f / 192, rem = f % 192, d = rem >> 6, o = rem & 63;
        if      (grp == 0) v = w10[o*138 + d]     - w10[o*138 + 6 + d];
        else if (grp == 1) v = w10[o*138 + 3 + d] + w10[o*138 + 6 + d];
        else if (grp == 2) v = wx1[o*10 + d]      - wx1[o*10 + 6 + d];
        else if (grp == 3) v = wx1[o*10 + 3 + d]  + wx1[o*10 + 6 + d];
        else if (grp == 4) v = wx2[o*10 + d]      - wx2[o*10 + 6 + d];
        else               v = wx2[o*10 + 3 + d]  + wx2[o*10 + 6 + d];
      }
      else if (f < 1216) v = w10[(f - 1152)*138 + 9];
      else if (f < 1280) v = wx1[(f - 1216)*10  + 9];
      else               v = wx2[(f - 1280)*10  + 9];
      ((float*)(ws + WS_F32))[f] = v;
    }
  }
}

__global__ __launch_bounds__(TPB, 1) void cvkernel(
    const float* __restrict__ xyz1, const float* __restrict__ feat1,
    const float* __restrict__ xyz2, const float* __restrict__ feat2,
    const float* __restrict__ b10v, const float* __restrict__ bx1v,
    const float* __restrict__ b11v, const float* __restrict__ b20v,
    const float* __restrict__ b21v, const float* __restrict__ bx2v,
    const float* __restrict__ b30v, const float* __restrict__ b31v,
    const char*  __restrict__ ws,   float* __restrict__ out)
{
  extern __shared__ __align__(16) char smem[];
  const int tid  = threadIdx.x;
  const int lane = tid & 63;
  const int wave = tid >> 6;
  const int l15  = lane & 15;
  const int lg   = lane >> 4;
  const int tile = blockIdx.x;
  const int b    = tile >> 8;
  const int s0   = (tile & 255) << 5;

  float* x1    = (float*)(smem + OFF_X1);
  float* x2    = (float*)(smem + OFF_X2);
  float* a1f   = (float*)(smem + OFF_A1F);
  float* a2f   = (float*)(smem + OFF_A2F);
  float* c1f   = (float*)(smem + OFF_C1F);
  float* c2f   = (float*)(smem + OFF_C2F);
  float* outb  = (float*)(smem + OFF_OUTB);
  float* biasL = (float*)(smem + OFF_BIAS);
  float* comb  = (float*)(smem + OFF_COMB);
  char*  aggB  = smem + OFF_AGGB;

  char* myA = smem + OFF_ACT + wave * 12288;
  char* myB = myA + 4096;
  char* myC = myA + 8192;

  // ---- stage constants into LDS ----
  { const uint4v* src = (const uint4v*)ws;
    uint4v*       dst = (uint4v*)smem;
    for (int i = tid; i < 3072; i += TPB) dst[i] = src[i]; }
  if (tid < 64){
    biasL[0*64+tid] = b10v[tid]; biasL[1*64+tid] = bx1v[tid];
    biasL[2*64+tid] = b11v[tid]; biasL[3*64+tid] = b20v[tid];
    biasL[4*64+tid] = b21v[tid]; biasL[5*64+tid] = bx2v[tid];
    biasL[6*64+tid] = b30v[tid]; biasL[7*64+tid] = b31v[tid];
  }
  { const float* src = (const float*)(ws + WS_F32);
    for (int i = tid; i < 1344; i += TPB) comb[i] = src[i]; }
  if (tid < 32){
#pragma unroll
    for (int d = 0; d < 3; ++d) x1[tid*4+d] = xyz1[(b*3+d)*S_LEN + s0 + tid];
    x1[tid*4+3] = 0.f;
  } else if (tid < 64){
    int p = tid - 32;
#pragma unroll
    for (int d = 0; d < 3; ++d) x2[p*4+d] = xyz2[(b*3+d)*S_LEN + s0 + p];
    x2[p*4+3] = 0.f;
  }
  for (int i = tid; i < 2048; i += TPB){
    int ch = i >> 5, p = i & 31;
    stBF(smem + OFF_F1B, p, ch, feat1[(b*64+ch)*S_LEN + s0 + p]);
    stBF(smem + OFF_F2B, p, ch, feat2[(b*64+ch)*S_LEN + s0 + p]);
  }
  __syncthreads();

  // ---- per-point precompute: a1 = Wf1*f1, a2 = Wf2*f2 (MFMA) ----
  {
    const char* Ab  = (wave < 2) ? (smem + OFF_F1B) : (smem + OFF_F2B);
    const char* Bg  = ws + ((wave < 2) ? WS_WF1 : WS_WF2);
    float* dstf     = (wave < 2) ? a1f : a2f;
    const int rt    = wave & 1;
    f32x4 acc[4];
#pragma unroll
    for (int cb = 0; cb < 4; ++cb) acc[cb] = (f32x4){0.f,0.f,0.f,0.f};
    gemm_k64(acc, Ab, Bg, rt * 16, lane);
#pragma unroll
    for (int cb = 0; cb < 4; ++cb)
#pragma unroll
      for (int v = 0; v < 4; ++v){
        int row = rt*16 + (lg << 2) + v;
        int col = (cb << 4) + l15;
        dstf[row*64 + col] = acc[cb][v];
      }
  }
  __syncthreads();
  // x-parts (K=3)
  for (int i = tid; i < 2048; i += TPB){
    int o = i & 63, p = i >> 6;
    float xa = x1[p*4], xb = x1[p*4+1], xc = x1[p*4+2];
    float ya = x2[p*4], yb = x2[p*4+1], yc = x2[p*4+2];
    a1f[p*64+o] += comb[      o]*xa + comb[ 64+o]*xb + comb[128+o]*xc;
    a2f[p*64+o] += comb[192+  o]*ya + comb[256+o]*yb + comb[320+o]*yc;
    c1f[p*64+o]  = comb[384+  o]*xa + comb[448+o]*xb + comb[512+o]*xc;
    c2f[p*64+o]  = comb[576+  o]*ya + comb[640+o]*yb + comb[704+o]*yc;
  }
  __syncthreads();

  // per-lane constants
  const int myc4 = l15 << 2;
  const float4v we4 = *(const float4v*)(comb + 1152 + myc4);
  const float4v ee4 = *(const float4v*)(comb + 1216 + myc4);
  const float4v ge4 = *(const float4v*)(comb + 1280 + myc4);
  const float4v b04 = *(const float4v*)(biasL + 0*64 + myc4);
  const float4v b14 = *(const float4v*)(biasL + 1*64 + myc4);
  const float4v b54 = *(const float4v*)(biasL + 5*64 + myc4);
  float b11r[4], b20r[4], b21r[4], b30r[4], b31r[4];
#pragma unroll
  for (int cb = 0; cb < 4; ++cb){
    b11r[cb] = biasL[2*64 + cb*16 + l15];
    b20r[cb] = biasL[3*64 + cb*16 + l15];
    b21r[cb] = biasL[4*64 + cb*16 + l15];
    b30r[cb] = biasL[6*64 + cb*16 + l15];
    b31r[cb] = biasL[7*64 + cb*16 + l15];
  }

  bf16x8 BW1[8], BW2[8];
  load_B8(BW1, smem + OFF_L11, lane);
  load_B8(BW2, smem + OFF_L21, lane);

  // ================= stage 1: 8 wave-local chunks, no barriers ============
  for (int cc = 0; cc < 8; ++cc){
    const int p  = wave*8 + cc;
    const float px = x1[p*4], py = x1[p*4+1], pz = x1[p*4+2];
    const float4v A1 = *(const float4v*)(a1f + p*64 + myc4);
    const float4v C1 = *(const float4v*)(c1f + p*64 + myc4);
    // build h1 -> myA, e -> myB (wave's 32 rows)
#pragma unroll
    for (int it = 0; it < 8; ++it){
      int q = it*4 + lg;
      float dx = x2[q*4]-px, dy = x2[q*4+1]-py, dz = x2[q*4+2]-pz;
      float eu = sqrtf(dx*dx + dy*dy + dz*dz + 1e-20f);
      float4v A2 = *(const float4v*)(a1f == a1f ? (a2f + q*64 + myc4) : nullptr);
      float4v C2 = *(const float4v*)(c2f + q*64 + myc4);
      float4v hv = A1 + A2 + we4*eu + b04;
      float4v ev = C1 + C2 + ee4*eu + b14;
      hv.x = fmaxf(hv.x,0.f); hv.y = fmaxf(hv.y,0.f); hv.z = fmaxf(hv.z,0.f); hv.w = fmaxf(hv.w,0.f);
      ev.x = fmaxf(ev.x,0.f); ev.y = fmaxf(ev.y,0.f); ev.z = fmaxf(ev.z,0.f); ev.w = fmaxf(ev.w,0.f);
      stBF4(myA, q, myc4, hv);
      stBF4(myB, q, myc4, ev);
    }
    // mlp1_1: h2 = relu(W11*h1 + b11) -> myC (+ f32 copy in regs)
    f32x4 acc[2][4];
#pragma unroll
    for (int t = 0; t < 2; ++t)
#pragma unroll
      for (int cb = 0; cb < 4; ++cb) acc[t][cb] = (f32x4){0.f,0.f,0.f,0.f};
    gemm32_k64(acc, myA, BW1, lane);
    float h2r[2][4][4];
#pragma unroll
    for (int t = 0; t < 2; ++t)
#pragma unroll
      for (int cb = 0; cb < 4; ++cb)
#pragma unroll
        for (int v = 0; v < 4; ++v){
          float h = fmaxf(acc[t][cb][v] + b11r[cb], 0.f);
          h2r[t][cb][v] = h;
          stBF(myC, t*16 + (lg<<2) + v, (cb<<4) + l15, h);
        }
    // mlp2_0: K=128 over [e(myB); h2(myC)]
#pragma unroll
    for (int t = 0; t < 2; ++t)
#pragma unroll
      for (int cb = 0; cb < 4; ++cb) acc[t][cb] = (f32x4){0.f,0.f,0.f,0.f};
    {
      bf16x8 Bt[8];
      load_B8(Bt, smem + OFF_L20, lane);
      gemm32_k64(acc, myB, Bt, lane);
      load_B8(Bt, smem + OFF_L20 + 8192, lane);
      gemm32_k64(acc, myC, Bt, lane);
    }
#pragma unroll
    for (int t = 0; t < 2; ++t)
#pragma unroll
      for (int cb = 0; cb < 4; ++cb)
#pragma unroll
        for (int v = 0; v < 4; ++v)
          stBF(myA, t*16 + (lg<<2) + v, (cb<<4) + l15,
               fmaxf(acc[t][cb][v] + b20r[cb], 0.f));
    // mlp2_1: logits in regs
#pragma unroll
    for (int t = 0; t < 2; ++t)
#pragma unroll
      for (int cb = 0; cb < 4; ++cb) acc[t][cb] = (f32x4){0.f,0.f,0.f,0.f};
    gemm32_k64(acc, myA, BW2, lane);
    // register softmax over the 32 q-rows + aggregation with f32 h2
    float mm[4], den[4], num[4];
#pragma unroll
    for (int cb = 0; cb < 4; ++cb) mm[cb] = -1e30f;
#pragma unroll
    for (int t = 0; t < 2; ++t)
#pragma unroll
      for (int cb = 0; cb < 4; ++cb)
#pragma unroll
        for (int v = 0; v < 4; ++v){
          float l = fmaxf(acc[t][cb][v] + b21r[cb], 0.f);
          acc[t][cb][v] = l;
          mm[cb] = fmaxf(mm[cb], l);
        }
#pragma unroll
    for (int cb = 0; cb < 4; ++cb){ mm[cb] = red_max(mm[cb]); den[cb] = 0.f; num[cb] = 0.f; }
#pragma unroll
    for (int t = 0; t < 2; ++t)
#pragma unroll
      for (int cb = 0; cb < 4; ++cb)
#pragma unroll
        for (int v = 0; v < 4; ++v){
          float e = __expf(acc[t][cb][v] - mm[cb]);
          den[cb] += e;
          num[cb] += e * h2r[t][cb][v];
        }
#pragma unroll
    for (int cb = 0; cb < 4; ++cb){ den[cb] = red_sum(den[cb]); num[cb] = red_sum(num[cb]); }
    if (lane < 16){
#pragma unroll
      for (int cb = 0; cb < 4; ++cb)
        stBF(aggB, p, (cb<<4) + lane, num[cb] / den[cb]);
    }
  }
  __syncthreads();

  // ---- stage-2 per-point precompute: d1/d2 (K=3), v1/v2 (MFMA) ----
  for (int i = tid; i < 2048; i += TPB){
    int o = i & 63, p = i >> 6;
    float xa = x1[p*4], xb = x1[p*4+1], xc = x1[p*4+2];
    c1f[p*64+o] = comb[768+o]*xa + comb[832+o]*xb + comb[896+o]*xc;
    c2f[p*64+o] = comb[960+o]*xa + comb[1024+o]*xb + comb[1088+o]*xc;
  }
  {
    const char* Ab = (wave < 2) ? (smem + OFF_F1B) : aggB;
    const char* Bg = ws + ((wave < 2) ? WS_W30B : WS_W30C);
    float* dstf    = (wave < 2) ? a1f : a2f;   // v1 / v2
    const int rt   = wave & 1;
    f32x4 acc[4];
#pragma unroll
    for (int cb = 0; cb < 4; ++cb) acc[cb] = (f32x4){0.f,0.f,0.f,0.f};
    gemm_k64(acc, Ab, Bg, rt*16, lane);
#pragma unroll
    for (int cb = 0; cb < 4; ++cb)
#pragma unroll
      for (int v = 0; v < 4; ++v){
        int row = rt*16 + (lg << 2) + v;
        int col = (cb << 4) + l15;
        dstf[row*64 + col] = acc[cb][v];
      }
  }
  __syncthreads();

  // ================= stage 2: 8 wave-local chunks, no barriers ============
  load_B8(BW1, smem + OFF_L30A, lane);
  load_B8(BW2, smem + OFF_L31, lane);
  for (int cc = 0; cc < 8; ++cc){
    const int p  = wave*8 + cc;
    const float px = x1[p*4], py = x1[p*4+1], pz = x1[p*4+2];
    const float4v C1 = *(const float4v*)(c1f + p*64 + myc4);
    float v1r[4];
#pragma unroll
    for (int cb = 0; cb < 4; ++cb) v1r[cb] = a1f[p*64 + (cb<<4) + l15];
    // e2 -> myA
#pragma unroll
    for (int it = 0; it < 8; ++it){
      int q = it*4 + lg;
      float dx = x1[q*4]-px, dy = x1[q*4+1]-py, dz = x1[q*4+2]-pz;
      float eu = sqrtf(dx*dx + dy*dy + dz*dz + 1e-20f);
      float4v C2 = *(const float4v*)(c2f + q*64 + myc4);
      float4v ev = C1 + C2 + ge4*eu + b54;
      ev.x = fmaxf(ev.x,0.f); ev.y = fmaxf(ev.y,0.f); ev.z = fmaxf(ev.z,0.f); ev.w = fmaxf(ev.w,0.f);
      stBF4(myA, q, myc4, ev);
    }
    // mlp3_0: c3 = relu(W30a*e2 + v1[p] + v2[q] + b30) -> myB
    f32x4 acc[2][4];
#pragma unroll
    for (int t = 0; t < 2; ++t)
#pragma unroll
      for (int cb = 0; cb < 4; ++cb) acc[t][cb] = (f32x4){0.f,0.f,0.f,0.f};
    gemm32_k64(acc, myA, BW1, lane);
#pragma unroll
    for (int t = 0; t < 2; ++t)
#pragma unroll
      for (int cb = 0; cb < 4; ++cb)
#pragma unroll
        for (int v = 0; v < 4; ++v){
          int q = t*16 + (lg<<2) + v;
          int col = (cb<<4) + l15;
          float c3 = acc[t][cb][v] + v1r[cb] + a2f[q*64+col] + b30r[cb];
          stBF(myB, q, col, fmaxf(c3, 0.f));
        }
    // mlp3_1: logits in regs
#pragma unroll
    for (int t = 0; t < 2; ++t)
#pragma unroll
      for (int cb = 0; cb < 4; ++cb) acc[t][cb] = (f32x4){0.f,0.f,0.f,0.f};
    gemm32_k64(acc, myB, BW2, lane);
    // masked register softmax (q != p) + output
    float mm[4], den[4], num[4];
#pragma unroll
    for (int cb = 0; cb < 4; ++cb) mm[cb] = -1e30f;
#pragma unroll
    for (int t = 0; t < 2; ++t)
#pragma unroll
      for (int cb = 0; cb < 4; ++cb)
#pragma unroll
        for (int v = 0; v < 4; ++v){
          int q = t*16 + (lg<<2) + v;
          float l = fmaxf(acc[t][cb][v] + b31r[cb], 0.f);
          l = (q == p) ? -1e30f : l;
          acc[t][cb][v] = l;
          mm[cb] = fmaxf(mm[cb], l);
        }
#pragma unroll
    for (int cb = 0; cb < 4; ++cb){ mm[cb] = red_max(mm[cb]); den[cb] = 0.f; num[cb] = 0.f; }
#pragma unroll
    for (int t = 0; t < 2; ++t)
#pragma unroll
      for (int cb = 0; cb < 4; ++cb)
#pragma unroll
        for (int v = 0; v < 4; ++v){
          int q = t*16 + (lg<<2) + v;
          float e = __expf(acc[t][cb][v] - mm[cb]);   // exp(-1e30-m)=0 masks q==p
          den[cb] += e;
          num[cb] += e * ldBF(aggB, q, (cb<<4) + l15);
        }
#pragma unroll
    for (int cb = 0; cb < 4; ++cb){ den[cb] = red_sum(den[cb]); num[cb] = red_sum(num[cb]); }
    if (lane < 16){
#pragma unroll
      for (int cb = 0; cb < 4; ++cb)
        outb[p*66 + (cb<<4) + lane] = num[cb] / den[cb];
    }
  }
  __syncthreads();

  // coalesced output write
  for (int i = tid; i < 2048; i += TPB){
    int ch = i >> 5, p = i & 31;
    out[(b*64 + ch)*S_LEN + s0 + p] = outb[p*66 + ch];
  }
}

extern "C" void kernel_launch(void* const* d_in, const int* in_sizes, int n_in,
                              void* d_out, int out_size, void* d_ws, size_t ws_size,
                              hipStream_t stream)
{
  const float* xyz1 = (const float*)d_in[0];
  const float* feat1= (const float*)d_in[1];
  const float* xyz2 = (const float*)d_in[2];
  const float* feat2= (const float*)d_in[3];
  const float* w10  = (const float*)d_in[4];
  const float* b10  = (const float*)d_in[5];
  const float* w11  = (const float*)d_in[6];
  const float* b11  = (const float*)d_in[7];
  const float* wx1  = (const float*)d_in[8];
  const float* bx1  = (const float*)d_in[9];
  const float* wx2  = (const float*)d_in[10];
  const float* bx2  = (const float*)d_in[11];
  const float* w20  = (const float*)d_in[12];
  const float* b20  = (const float*)d_in[13];
  const float* w21  = (const float*)d_in[14];
  const float* b21  = (const float*)d_in[15];
  const float* w30  = (const float*)d_in[16];
  const float* b30  = (const float*)d_in[17];
  const float* w31  = (const float*)d_in[18];
  const float* b31  = (const float*)d_in[19];

  (void)hipFuncSetAttribute(reinterpret_cast<const void*>(cvkernel),
                            hipFuncAttributeMaxDynamicSharedMemorySize, LDS_TOTAL);

  hipLaunchKernelGGL(pack_weights, dim3(64), dim3(256), 0, stream,
                     w10, w11, wx1, wx2, w20, w21, w30, w31, (unsigned char*)d_ws);
  hipLaunchKernelGGL(cvkernel, dim3(512), dim3(TPB), LDS_TOTAL, stream,
                     xyz1, feat1, xyz2, feat2,
                     b10, bx1, b11, b20, b21, bx2, b30, b31,
                     (const char*)d_ws, (float*)d_out);
}